// Round 1
// 1891.150 us; speedup vs baseline: 1.3016x; 1.3016x over previous
//
#include <hip/hip_runtime.h>
#include <hip/hip_bf16.h>
#include <cmath>

// ---------------------------------------------------------------------------
// Pipeline: y1 = bn_relu(dcn(x, w_off1, b_off1, w1, b1))        (4,128,64,64)
//           up = up_depthwise(y1, w_up, f=2)                    (4,128,128,128)
//           out = bn_relu(dcn(up, w_off2, b_off2, w2, b2))      (4,128,128,128)
// All fp32. Workspace: om1 | y1 | up | om2  (50.8 MB total)
// ---------------------------------------------------------------------------

#define EPSV 1e-5f

// ---------------- offset conv: 3x3, pad 1, 27 output channels ---------------
template <int CIN, int HH, int WW>
__global__ __launch_bounds__(256) void conv_off_kernel(
    const float* __restrict__ in,    // (B, CIN, HH, WW)
    const float* __restrict__ wt,    // (27, CIN, 3, 3)
    const float* __restrict__ bias,  // (27)
    float* __restrict__ om)          // (B, 27, HH, WW)
{
    const int hw = blockIdx.x * 256 + threadIdx.x;   // gridDim.x = HH*WW/256
    const int o  = blockIdx.y;                        // 27
    const int b  = blockIdx.z;                        // B
    const int y  = hw / WW;
    const int x  = hw - y * WW;

    const float* ip = in + (size_t)b * CIN * HH * WW;
    const float* wp = wt + (size_t)o * CIN * 9;

    float acc = bias[o];
    for (int c = 0; c < CIN; ++c) {
        const float* chp = ip + (size_t)c * HH * WW;
        const float* wc  = wp + c * 9;
#pragma unroll
        for (int r = 0; r < 3; ++r) {
            const int iy = y + r - 1;
            if (iy < 0 || iy >= HH) continue;
#pragma unroll
            for (int s = 0; s < 3; ++s) {
                const int ix = x + s - 1;
                if (ix < 0 || ix >= WW) continue;
                acc += chp[iy * WW + ix] * wc[r * 3 + s];
            }
        }
    }
    om[(size_t)(b * 27 + o) * (HH * WW) + hw] = acc;
}

// ---------------- fused DCN: sample + mask + GEMM + bias + BN + ReLU --------
// Block: 256 threads, one (b, TP-position tile). Out = (B, 128, HH*WW).
// CC=4 channels/chunk -> CK=36, LDS ~35KB (TP=64) -> 4 blocks/CU.
// Asub transposed to [kk][co] (stride 132) so per-thread A loads are vector.
// TP=64: acc 8co x 4pos. TP=16 (small HW, need grid): acc 2co x 4pos.
template <int CIN, int HH, int WW, int TP>
__global__ __launch_bounds__(256, 4) void dcn_kernel(
    const float* __restrict__ xin,   // (B, CIN, HH, WW)
    const float* __restrict__ om,    // (B, 27, HH, WW)
    const float* __restrict__ wmat,  // (128, CIN, 9)
    const float* __restrict__ bias,  // (128)
    const float* __restrict__ gam, const float* __restrict__ bet,
    const float* __restrict__ mu,  const float* __restrict__ var,
    float* __restrict__ out)         // (B, 128, HH*WW)
{
    constexpr int HW  = HH * WW;
    constexpr int CO  = 128;
    constexpr int CC  = 4;           // channels per chunk
    constexpr int CK  = CC * 9;      // 36
    constexpr int AS  = CO + 4;      // Asub row stride (pad 4: banks spread)
    constexpr int PG  = TP / 4;      // position groups (float4 each)
    constexpr int OPT = TP / 8;      // output channels per thread

    __shared__ float offy[9 * TP];
    __shared__ float offx[9 * TP];
    __shared__ float msk[9 * TP];
    __shared__ __align__(16) float Asub[CK * AS];    // [kk][co]
    __shared__ __align__(16) float Bsub[CK * TP];    // [kk][pos]

    const int tid = threadIdx.x;
    const int nt  = HW / TP;
    const int b   = blockIdx.x / nt;
    const int p0  = (blockIdx.x - b * nt) * TP;

    // stage offsets / mask for this position tile
    const float* omb = om + (size_t)b * 27 * HW;
    for (int i = tid; i < 9 * TP; i += 256) {
        const int k  = i / TP;
        const int pp = i - k * TP;
        const int p  = p0 + pp;
        offy[i] = omb[(size_t)k * HW + p];
        offx[i] = omb[(size_t)(9 + k) * HW + p];
        const float mv = omb[(size_t)(18 + k) * HW + p];
        msk[i] = 1.0f / (1.0f + expf(-mv));
    }
    __syncthreads();

    const float* xb = xin + (size_t)b * CIN * HW;
    const int og = tid / PG;          // output-channel group
    const int o0 = og * OPT;
    const int pt = (tid - og * PG) * 4;

    float acc[OPT][4];
#pragma unroll
    for (int i = 0; i < OPT; ++i)
#pragma unroll
        for (int j = 0; j < 4; ++j) acc[i][j] = 0.f;

    for (int cc = 0; cc < CIN; cc += CC) {
        // ---- stage A: weight chunk, transposed to [kk][co] ----
        for (int i = tid; i < CO * CK; i += 256) {
            const int row = i / CK;           // co
            const int col = i - row * CK;     // kk
            Asub[col * AS + row] =
                wmat[(size_t)row * CIN * 9 + cc * 9 + col];
        }
        // ---- stage B: bilinear-sampled, masked values (CK x TP) ----
        for (int i = tid; i < CK * TP; i += 256) {
            const int kk = i / TP;            // 0..CK-1
            const int pp = i - kk * TP;
            const int cq = kk / 9;
            const int k  = kk - cq * 9;
            const int c  = cc + cq;
            const int p  = p0 + pp;
            const int yy = p / WW;
            const int xx = p - yy * WW;
            const float py = (float)(yy + (k / 3) - 1) + offy[k * TP + pp];
            const float px = (float)(xx + (k % 3) - 1) + offx[k * TP + pp];
            const float y0f = floorf(py);
            const float x0f = floorf(px);
            const int   y0  = (int)y0f;
            const int   x0  = (int)x0f;
            const float wy1 = py - y0f, wy0 = 1.f - wy1;
            const float wx1 = px - x0f, wx0 = 1.f - wx1;
            const bool y0v = (y0 >= 0) && (y0 < HH);
            const bool y1v = (y0 + 1 >= 0) && (y0 + 1 < HH);
            const bool x0v = (x0 >= 0) && (x0 < WW);
            const bool x1v = (x0 + 1 >= 0) && (x0 + 1 < WW);
            const float* chp = xb + (size_t)c * HW;
            float s = 0.f;
            if (y0v && x0v) s += chp[y0 * WW + x0]           * wy0 * wx0;
            if (y0v && x1v) s += chp[y0 * WW + x0 + 1]       * wy0 * wx1;
            if (y1v && x0v) s += chp[(y0 + 1) * WW + x0]     * wy1 * wx0;
            if (y1v && x1v) s += chp[(y0 + 1) * WW + x0 + 1] * wy1 * wx1;
            Bsub[kk * TP + pp] = s * msk[k * TP + pp];
        }
        __syncthreads();

        // ---- register-tiled FMA: acc[OPT][4] += A[OPT][CK] * B[CK][4] ----
        for (int kk = 0; kk < CK; ++kk) {
            const float* ap = &Asub[kk * AS + o0];
            float a[OPT];
            if constexpr (OPT == 8) {
                const float4 t0 = *reinterpret_cast<const float4*>(ap);
                const float4 t1 = *reinterpret_cast<const float4*>(ap + 4);
                a[0] = t0.x; a[1] = t0.y; a[2] = t0.z; a[3] = t0.w;
                a[4] = t1.x; a[5] = t1.y; a[6] = t1.z; a[7] = t1.w;
            } else {
                const float2 t0 = *reinterpret_cast<const float2*>(ap);
                a[0] = t0.x; a[1] = t0.y;
            }
            const float4 bv =
                *reinterpret_cast<const float4*>(&Bsub[kk * TP + pt]);
#pragma unroll
            for (int i = 0; i < OPT; ++i) {
                acc[i][0] += a[i] * bv.x;
                acc[i][1] += a[i] * bv.y;
                acc[i][2] += a[i] * bv.z;
                acc[i][3] += a[i] * bv.w;
            }
        }
        __syncthreads();
    }

    // ---- epilogue: + conv bias, BN, ReLU ----
    float* outb = out + (size_t)b * CO * HW;
#pragma unroll
    for (int i = 0; i < OPT; ++i) {
        const int o = o0 + i;
        const float inv = gam[o] * rsqrtf(var[o] + EPSV);
        const float sh  = bet[o] - mu[o] * inv + bias[o] * inv;
        float4 r;
        r.x = fmaxf(acc[i][0] * inv + sh, 0.f);
        r.y = fmaxf(acc[i][1] * inv + sh, 0.f);
        r.z = fmaxf(acc[i][2] * inv + sh, 0.f);
        r.w = fmaxf(acc[i][3] * inv + sh, 0.f);
        *reinterpret_cast<float4*>(&outb[(size_t)o * HW + p0 + pt]) = r;
    }
}

// ---------------- depthwise transposed-conv upsample x2 (k=4, pad 2) --------
__global__ __launch_bounds__(256) void upsample_kernel(
    const float* __restrict__ y,    // (4,128,64,64)
    const float* __restrict__ wup,  // (128,1,4,4)
    float* __restrict__ out)        // (4,128,128,128)
{
    const int idx = blockIdx.x * 256 + threadIdx.x;   // 8388608 total
    const int ox = idx & 127;
    const int oy = (idx >> 7) & 127;
    const int c  = (idx >> 14) & 127;
    const int b  = idx >> 21;

    const float* yc = y + (size_t)(b * 128 + c) * 4096;
    const float* wc = wup + c * 16;

    float acc = 0.f;
#pragma unroll
    for (int ky = 0; ky < 4; ++ky) {
        const int qy = oy + ky - 2;
        if (qy & 1) continue;
        const int iy = qy >> 1;
        if (iy < 0 || iy >= 64) continue;
#pragma unroll
        for (int kx = 0; kx < 4; ++kx) {
            const int qx = ox + kx - 2;
            if (qx & 1) continue;
            const int ix = qx >> 1;
            if (ix < 0 || ix >= 64) continue;
            acc += yc[iy * 64 + ix] * wc[(3 - ky) * 4 + (3 - kx)];
        }
    }
    out[idx] = acc;
}

// ---------------------------------------------------------------------------
extern "C" void kernel_launch(void* const* d_in, const int* in_sizes, int n_in,
                              void* d_out, int out_size, void* d_ws, size_t ws_size,
                              hipStream_t stream) {
    const float* x      = (const float*)d_in[0];
    const float* w_off1 = (const float*)d_in[1];
    const float* b_off1 = (const float*)d_in[2];
    const float* w1     = (const float*)d_in[3];
    const float* b1     = (const float*)d_in[4];
    const float* g1v    = (const float*)d_in[5];
    const float* be1    = (const float*)d_in[6];
    const float* m1     = (const float*)d_in[7];
    const float* v1     = (const float*)d_in[8];
    const float* w_up   = (const float*)d_in[9];
    const float* w_off2 = (const float*)d_in[10];
    const float* b_off2 = (const float*)d_in[11];
    const float* w2     = (const float*)d_in[12];
    const float* b2     = (const float*)d_in[13];
    const float* g2v    = (const float*)d_in[14];
    const float* be2    = (const float*)d_in[15];
    const float* m2     = (const float*)d_in[16];
    const float* v2     = (const float*)d_in[17];

    float* ws  = (float*)d_ws;
    float* om1 = ws;                     // 4*27*4096   =   442368 f
    float* y1  = om1 + 442368;           // 4*128*4096  =  2097152 f
    float* up  = y1 + 2097152;           // 4*128*16384 =  8388608 f
    float* om2 = up + 8388608;           // 4*27*16384  =  1769472 f
    float* outf = (float*)d_out;

    {   // om1 = conv3x3(x, w_off1) + b_off1
        dim3 grid(4096 / 256, 27, 4);
        conv_off_kernel<256, 64, 64><<<grid, 256, 0, stream>>>(x, w_off1, b_off1, om1);
    }
    // y1 = bn_relu(dcn1)  — TP=16 -> 1024 blocks (was 256: 1 block/CU!)
    dcn_kernel<256, 64, 64, 16><<<4 * (4096 / 16), 256, 0, stream>>>(
        x, om1, w1, b1, g1v, be1, m1, v1, y1);
    // up = depthwise transposed upsample
    upsample_kernel<<<8388608 / 256, 256, 0, stream>>>(y1, w_up, up);
    {   // om2 = conv3x3(up, w_off2) + b_off2
        dim3 grid(16384 / 256, 27, 4);
        conv_off_kernel<128, 128, 128><<<grid, 256, 0, stream>>>(up, w_off2, b_off2, om2);
    }
    // out = bn_relu(dcn2)  — TP=64, CC=4 -> ~35KB LDS -> 4 blocks/CU
    dcn_kernel<128, 128, 128, 64><<<4 * (16384 / 64), 256, 0, stream>>>(
        up, om2, w2, b2, g2v, be2, m2, v2, outf);
}

// Round 2
// 1292.106 us; speedup vs baseline: 1.9051x; 1.4636x over previous
//
#include <hip/hip_runtime.h>
#include <hip/hip_bf16.h>
#include <cmath>

// ---------------------------------------------------------------------------
// Pipeline: y1 = bn_relu(dcn(x, w_off1, b_off1, w1, b1))        (4,128,64,64)
//           up = up_depthwise(y1, w_up, f=2)                    (4,128,128,128)
//           out = bn_relu(dcn(up, w_off2, b_off2, w2, b2))      (4,128,128,128)
// All fp32. Workspace: om1 | y1 | up | om2  (50.8 MB total)
// ---------------------------------------------------------------------------

#define EPSV 1e-5f

// ---------------- offset conv: 3x3, pad 1, 27 output channels ---------------
// One block per (image row, batch). POS = WW threads per channel-group,
// SPLIT channel groups in-block. Input rows staged in LDS (reused by all 27
// outputs); weights via scalar loads (block-uniform index). Deterministic
// in-block LDS reduce over groups + bias. No atomics, no extra workspace.
template <int CIN, int HH, int WW, int SPLIT, int CC>
__global__ __launch_bounds__(WW * SPLIT) void conv_off_kernel(
    const float* __restrict__ in,    // (B, CIN, HH, WW)
    const float* __restrict__ wt,    // (27, CIN, 3, 3)
    const float* __restrict__ bias,  // (27)
    float* __restrict__ om)          // (B, 27, HH, WW)
{
    constexpr int POS  = WW;             // one full row per tile
    constexpr int NT   = WW * SPLIT;     // threads
    constexpr int CPG  = CIN / SPLIT;    // channels per group
    constexpr int NCH  = CPG / CC;       // chunks per group
    constexpr int SLABN = SPLIT * CC * 3 * POS;
    constexpr int REDN  = 27 * SPLIT * POS;
    constexpr int SMEMN = (SLABN > REDN) ? SLABN : REDN;

    __shared__ __align__(16) float smem[SMEMN];
    float* slab = smem;                  // [g][cc][3][POS]  (chunk phase)
    float* red  = smem;                  // [o][g][POS]      (reduce phase)

    const int tid = threadIdx.x;
    const int pos = tid & (POS - 1);
    const int g   = tid / POS;           // wave-uniform (POS is 64 or 128)
    const int row = blockIdx.x;          // 0..HH-1
    const int b   = blockIdx.y;

    const float* ib = in + (size_t)b * CIN * HH * WW;
    // scalar channel base for this group -> weight indices become SGPR exprs
    const int cbs = __builtin_amdgcn_readfirstlane(g * CPG);

    float acc[27];
#pragma unroll
    for (int o = 0; o < 27; ++o) acc[o] = 0.f;

    for (int ch = 0; ch < NCH; ++ch) {
        const int c0 = ch * CC;          // chunk base within group
        // ---- stage: SPLIT*CC channels x 3 rows x POS cols, coalesced ----
        for (int i = tid; i < SLABN; i += NT) {
            const int gg = i / (CC * 3 * POS);
            const int r1 = i - gg * (CC * 3 * POS);
            const int cc = r1 / (3 * POS);
            const int r2 = r1 - cc * 3 * POS;
            const int rr = r2 / POS;
            const int px = r2 - rr * POS;
            const int c  = gg * CPG + c0 + cc;
            const int iy = row + rr - 1;
            float v = 0.f;
            if (iy >= 0 && iy < HH) v = ib[((size_t)c * HH + iy) * WW + px];
            slab[i] = v;
        }
        __syncthreads();

        // ---- compute: per channel, 9 LDS reads then 27x9 scalar-weight FMAs
        const float* myslab = slab + g * (CC * 3 * POS);
        for (int cc = 0; cc < CC; ++cc) {
            const float* sl = myslab + cc * 3 * POS;
            float v[9];
            const int xm = (pos > 0) ? pos - 1 : 0;
            const int xp = (pos < POS - 1) ? pos + 1 : POS - 1;
#pragma unroll
            for (int r = 0; r < 3; ++r) {
                const float tl = sl[r * POS + xm];
                const float tc = sl[r * POS + pos];
                const float tr = sl[r * POS + xp];
                v[r * 3 + 0] = (pos > 0) ? tl : 0.f;
                v[r * 3 + 1] = tc;
                v[r * 3 + 2] = (pos < POS - 1) ? tr : 0.f;
            }
            const float* wp = wt + (size_t)(cbs + c0 + cc) * 9;
#pragma unroll
            for (int o = 0; o < 27; ++o) {
                const float* w9 = wp + (size_t)o * CIN * 9;
#pragma unroll
                for (int k = 0; k < 9; ++k)
                    acc[o] = fmaf(w9[k], v[k], acc[o]);
            }
        }
        __syncthreads();
    }

    // ---- in-block reduce over channel groups (deterministic, g ascending) --
#pragma unroll
    for (int o = 0; o < 27; ++o) red[(o * SPLIT + g) * POS + pos] = acc[o];
    __syncthreads();

    float* ob = om + (size_t)b * 27 * HH * WW + (size_t)row * WW;
    for (int i = tid; i < 27 * POS; i += NT) {
        const int o  = i / POS;
        const int px = i - o * POS;
        float s = bias[o];
#pragma unroll
        for (int gg = 0; gg < SPLIT; ++gg)
            s += red[(o * SPLIT + gg) * POS + px];
        ob[(size_t)o * HH * WW + px] = s;
    }
}

// ---------------- fused DCN: sample + mask + GEMM + bias + BN + ReLU --------
// Block: 256 threads, one (b, TP-position tile). Out = (B, 128, HH*WW).
// CC=4 channels/chunk -> CK=36, LDS ~35KB (TP=64) -> 4 blocks/CU.
// Asub transposed to [kk][co] (stride 132) so per-thread A loads are vector.
// TP=64: acc 8co x 4pos. TP=16 (small HW, need grid): acc 2co x 4pos.
template <int CIN, int HH, int WW, int TP>
__global__ __launch_bounds__(256, 4) void dcn_kernel(
    const float* __restrict__ xin,   // (B, CIN, HH, WW)
    const float* __restrict__ om,    // (B, 27, HH, WW)
    const float* __restrict__ wmat,  // (128, CIN, 9)
    const float* __restrict__ bias,  // (128)
    const float* __restrict__ gam, const float* __restrict__ bet,
    const float* __restrict__ mu,  const float* __restrict__ var,
    float* __restrict__ out)         // (B, 128, HH*WW)
{
    constexpr int HW  = HH * WW;
    constexpr int CO  = 128;
    constexpr int CC  = 4;           // channels per chunk
    constexpr int CK  = CC * 9;      // 36
    constexpr int AS  = CO + 4;      // Asub row stride (pad 4: banks spread)
    constexpr int PG  = TP / 4;      // position groups (float4 each)
    constexpr int OPT = TP / 8;      // output channels per thread

    __shared__ float offy[9 * TP];
    __shared__ float offx[9 * TP];
    __shared__ float msk[9 * TP];
    __shared__ __align__(16) float Asub[CK * AS];    // [kk][co]
    __shared__ __align__(16) float Bsub[CK * TP];    // [kk][pos]

    const int tid = threadIdx.x;
    const int nt  = HW / TP;
    const int b   = blockIdx.x / nt;
    const int p0  = (blockIdx.x - b * nt) * TP;

    // stage offsets / mask for this position tile
    const float* omb = om + (size_t)b * 27 * HW;
    for (int i = tid; i < 9 * TP; i += 256) {
        const int k  = i / TP;
        const int pp = i - k * TP;
        const int p  = p0 + pp;
        offy[i] = omb[(size_t)k * HW + p];
        offx[i] = omb[(size_t)(9 + k) * HW + p];
        const float mv = omb[(size_t)(18 + k) * HW + p];
        msk[i] = 1.0f / (1.0f + expf(-mv));
    }
    __syncthreads();

    const float* xb = xin + (size_t)b * CIN * HW;
    const int og = tid / PG;          // output-channel group
    const int o0 = og * OPT;
    const int pt = (tid - og * PG) * 4;

    float acc[OPT][4];
#pragma unroll
    for (int i = 0; i < OPT; ++i)
#pragma unroll
        for (int j = 0; j < 4; ++j) acc[i][j] = 0.f;

    for (int cc = 0; cc < CIN; cc += CC) {
        // ---- stage A: weight chunk, transposed to [kk][co] ----
        for (int i = tid; i < CO * CK; i += 256) {
            const int row = i / CK;           // co
            const int col = i - row * CK;     // kk
            Asub[col * AS + row] =
                wmat[(size_t)row * CIN * 9 + cc * 9 + col];
        }
        // ---- stage B: bilinear-sampled, masked values (CK x TP) ----
        for (int i = tid; i < CK * TP; i += 256) {
            const int kk = i / TP;            // 0..CK-1
            const int pp = i - kk * TP;
            const int cq = kk / 9;
            const int k  = kk - cq * 9;
            const int c  = cc + cq;
            const int p  = p0 + pp;
            const int yy = p / WW;
            const int xx = p - yy * WW;
            const float py = (float)(yy + (k / 3) - 1) + offy[k * TP + pp];
            const float px = (float)(xx + (k % 3) - 1) + offx[k * TP + pp];
            const float y0f = floorf(py);
            const float x0f = floorf(px);
            const int   y0  = (int)y0f;
            const int   x0  = (int)x0f;
            const float wy1 = py - y0f, wy0 = 1.f - wy1;
            const float wx1 = px - x0f, wx0 = 1.f - wx1;
            const bool y0v = (y0 >= 0) && (y0 < HH);
            const bool y1v = (y0 + 1 >= 0) && (y0 + 1 < HH);
            const bool x0v = (x0 >= 0) && (x0 < WW);
            const bool x1v = (x0 + 1 >= 0) && (x0 + 1 < WW);
            const float* chp = xb + (size_t)c * HW;
            float s = 0.f;
            if (y0v && x0v) s += chp[y0 * WW + x0]           * wy0 * wx0;
            if (y0v && x1v) s += chp[y0 * WW + x0 + 1]       * wy0 * wx1;
            if (y1v && x0v) s += chp[(y0 + 1) * WW + x0]     * wy1 * wx0;
            if (y1v && x1v) s += chp[(y0 + 1) * WW + x0 + 1] * wy1 * wx1;
            Bsub[kk * TP + pp] = s * msk[k * TP + pp];
        }
        __syncthreads();

        // ---- register-tiled FMA: acc[OPT][4] += A[OPT][CK] * B[CK][4] ----
        for (int kk = 0; kk < CK; ++kk) {
            const float* ap = &Asub[kk * AS + o0];
            float a[OPT];
            if constexpr (OPT == 8) {
                const float4 t0 = *reinterpret_cast<const float4*>(ap);
                const float4 t1 = *reinterpret_cast<const float4*>(ap + 4);
                a[0] = t0.x; a[1] = t0.y; a[2] = t0.z; a[3] = t0.w;
                a[4] = t1.x; a[5] = t1.y; a[6] = t1.z; a[7] = t1.w;
            } else {
                const float2 t0 = *reinterpret_cast<const float2*>(ap);
                a[0] = t0.x; a[1] = t0.y;
            }
            const float4 bv =
                *reinterpret_cast<const float4*>(&Bsub[kk * TP + pt]);
#pragma unroll
            for (int i = 0; i < OPT; ++i) {
                acc[i][0] += a[i] * bv.x;
                acc[i][1] += a[i] * bv.y;
                acc[i][2] += a[i] * bv.z;
                acc[i][3] += a[i] * bv.w;
            }
        }
        __syncthreads();
    }

    // ---- epilogue: + conv bias, BN, ReLU ----
    float* outb = out + (size_t)b * CO * HW;
#pragma unroll
    for (int i = 0; i < OPT; ++i) {
        const int o = o0 + i;
        const float inv = gam[o] * rsqrtf(var[o] + EPSV);
        const float sh  = bet[o] - mu[o] * inv + bias[o] * inv;
        float4 r;
        r.x = fmaxf(acc[i][0] * inv + sh, 0.f);
        r.y = fmaxf(acc[i][1] * inv + sh, 0.f);
        r.z = fmaxf(acc[i][2] * inv + sh, 0.f);
        r.w = fmaxf(acc[i][3] * inv + sh, 0.f);
        *reinterpret_cast<float4*>(&outb[(size_t)o * HW + p0 + pt]) = r;
    }
}

// ---------------- depthwise transposed-conv upsample x2 (k=4, pad 2) --------
__global__ __launch_bounds__(256) void upsample_kernel(
    const float* __restrict__ y,    // (4,128,64,64)
    const float* __restrict__ wup,  // (128,1,4,4)
    float* __restrict__ out)        // (4,128,128,128)
{
    const int idx = blockIdx.x * 256 + threadIdx.x;   // 8388608 total
    const int ox = idx & 127;
    const int oy = (idx >> 7) & 127;
    const int c  = (idx >> 14) & 127;
    const int b  = idx >> 21;

    const float* yc = y + (size_t)(b * 128 + c) * 4096;
    const float* wc = wup + c * 16;

    float acc = 0.f;
#pragma unroll
    for (int ky = 0; ky < 4; ++ky) {
        const int qy = oy + ky - 2;
        if (qy & 1) continue;
        const int iy = qy >> 1;
        if (iy < 0 || iy >= 64) continue;
#pragma unroll
        for (int kx = 0; kx < 4; ++kx) {
            const int qx = ox + kx - 2;
            if (qx & 1) continue;
            const int ix = qx >> 1;
            if (ix < 0 || ix >= 64) continue;
            acc += yc[iy * 64 + ix] * wc[(3 - ky) * 4 + (3 - kx)];
        }
    }
    out[idx] = acc;
}

// ---------------------------------------------------------------------------
extern "C" void kernel_launch(void* const* d_in, const int* in_sizes, int n_in,
                              void* d_out, int out_size, void* d_ws, size_t ws_size,
                              hipStream_t stream) {
    const float* x      = (const float*)d_in[0];
    const float* w_off1 = (const float*)d_in[1];
    const float* b_off1 = (const float*)d_in[2];
    const float* w1     = (const float*)d_in[3];
    const float* b1     = (const float*)d_in[4];
    const float* g1v    = (const float*)d_in[5];
    const float* be1    = (const float*)d_in[6];
    const float* m1     = (const float*)d_in[7];
    const float* v1     = (const float*)d_in[8];
    const float* w_up   = (const float*)d_in[9];
    const float* w_off2 = (const float*)d_in[10];
    const float* b_off2 = (const float*)d_in[11];
    const float* w2     = (const float*)d_in[12];
    const float* b2     = (const float*)d_in[13];
    const float* g2v    = (const float*)d_in[14];
    const float* be2    = (const float*)d_in[15];
    const float* m2     = (const float*)d_in[16];
    const float* v2     = (const float*)d_in[17];

    float* ws  = (float*)d_ws;
    float* om1 = ws;                     // 4*27*4096   =   442368 f
    float* y1  = om1 + 442368;           // 4*128*4096  =  2097152 f
    float* up  = y1 + 2097152;           // 4*128*16384 =  8388608 f
    float* om2 = up + 8388608;           // 4*27*16384  =  1769472 f
    float* outf = (float*)d_out;

    {   // om1 = conv3x3(x, w_off1) + b_off1 — 1 block/row, 8-way ch split
        dim3 grid(64, 4);
        conv_off_kernel<256, 64, 64, 8, 8><<<grid, 512, 0, stream>>>(
            x, w_off1, b_off1, om1);
    }
    // y1 = bn_relu(dcn1)  — TP=16 -> 1024 blocks
    dcn_kernel<256, 64, 64, 16><<<4 * (4096 / 16), 256, 0, stream>>>(
        x, om1, w1, b1, g1v, be1, m1, v1, y1);
    // up = depthwise transposed upsample
    upsample_kernel<<<8388608 / 256, 256, 0, stream>>>(y1, w_up, up);
    {   // om2 = conv3x3(up, w_off2) + b_off2 — 1 block/row, 2-way ch split
        dim3 grid(128, 4);
        conv_off_kernel<128, 128, 128, 2, 8><<<grid, 256, 0, stream>>>(
            up, w_off2, b_off2, om2);
    }
    // out = bn_relu(dcn2)  — TP=64, CC=4 -> ~35KB LDS -> 4 blocks/CU
    dcn_kernel<128, 128, 128, 64><<<4 * (16384 / 64), 256, 0, stream>>>(
        up, om2, w2, b2, g2v, be2, m2, v2, outf);
}

// Round 3
// 1270.823 us; speedup vs baseline: 1.9370x; 1.0167x over previous
//
#include <hip/hip_runtime.h>
#include <hip/hip_bf16.h>
#include <cmath>

// ---------------------------------------------------------------------------
// Pipeline: y1 = bn_relu(dcn(x, w_off1, b_off1, w1, b1))        (4,128,64,64)
//           up = up_depthwise(y1, w_up, f=2)                    (4,128,128,128)
//           out = bn_relu(dcn(up, w_off2, b_off2, w2, b2))      (4,128,128,128)
// DCN GEMM on mfma_f32_16x16x32_bf16 with split-bf16 (hi/lo, 3 products).
// Workspace: om1 | y1 | up | om2 ; w1-split parked in `up` (dead until
// upsample), w2-split parked in `y1` (dead after upsample).
// ---------------------------------------------------------------------------

#define EPSV 1e-5f

typedef __attribute__((ext_vector_type(8))) short short8;
typedef __attribute__((ext_vector_type(4))) float f32x4;

__device__ __forceinline__ ushort f2bf(float f) {
    union { float f; uint u; } v; v.f = f;
    const uint r = v.u + 0x7fffu + ((v.u >> 16) & 1u);   // RNE
    return (ushort)(r >> 16);
}
__device__ __forceinline__ float bf2f(ushort h) {
    union { uint u; float f; } v; v.u = ((uint)h) << 16;
    return v.f;
}

// ---------------- weight split: fp32 -> bf16 hi/lo --------------------------
__global__ __launch_bounds__(256) void wsplit_kernel(
    const float* __restrict__ w, ushort* __restrict__ hi,
    ushort* __restrict__ lo, int n)
{
    const int i = blockIdx.x * 256 + threadIdx.x;
    if (i >= n) return;
    const float f = w[i];
    const ushort h = f2bf(f);
    hi[i] = h;
    lo[i] = f2bf(f - bf2f(h));
}

// ---------------- offset conv: 3x3, pad 1, 27 output channels ---------------
template <int CIN, int HH, int WW, int SPLIT, int CC>
__global__ __launch_bounds__(WW * SPLIT) void conv_off_kernel(
    const float* __restrict__ in,    // (B, CIN, HH, WW)
    const float* __restrict__ wt,    // (27, CIN, 3, 3)
    const float* __restrict__ bias,  // (27)
    float* __restrict__ om)          // (B, 27, HH, WW)
{
    constexpr int POS  = WW;
    constexpr int NT   = WW * SPLIT;
    constexpr int CPG  = CIN / SPLIT;
    constexpr int NCH  = CPG / CC;
    constexpr int SLABN = SPLIT * CC * 3 * POS;
    constexpr int REDN  = 27 * SPLIT * POS;
    constexpr int SMEMN = (SLABN > REDN) ? SLABN : REDN;

    __shared__ __align__(16) float smem[SMEMN];
    float* slab = smem;
    float* red  = smem;

    const int tid = threadIdx.x;
    const int pos = tid & (POS - 1);
    const int g   = tid / POS;
    const int row = blockIdx.x;
    const int b   = blockIdx.y;

    const float* ib = in + (size_t)b * CIN * HH * WW;
    const int cbs = __builtin_amdgcn_readfirstlane(g * CPG);

    float acc[27];
#pragma unroll
    for (int o = 0; o < 27; ++o) acc[o] = 0.f;

    for (int ch = 0; ch < NCH; ++ch) {
        const int c0 = ch * CC;
        for (int i = tid; i < SLABN; i += NT) {
            const int gg = i / (CC * 3 * POS);
            const int r1 = i - gg * (CC * 3 * POS);
            const int cc = r1 / (3 * POS);
            const int r2 = r1 - cc * 3 * POS;
            const int rr = r2 / POS;
            const int px = r2 - rr * POS;
            const int c  = gg * CPG + c0 + cc;
            const int iy = row + rr - 1;
            float v = 0.f;
            if (iy >= 0 && iy < HH) v = ib[((size_t)c * HH + iy) * WW + px];
            slab[i] = v;
        }
        __syncthreads();

        const float* myslab = slab + g * (CC * 3 * POS);
        for (int cc = 0; cc < CC; ++cc) {
            const float* sl = myslab + cc * 3 * POS;
            float v[9];
            const int xm = (pos > 0) ? pos - 1 : 0;
            const int xp = (pos < POS - 1) ? pos + 1 : POS - 1;
#pragma unroll
            for (int r = 0; r < 3; ++r) {
                const float tl = sl[r * POS + xm];
                const float tc = sl[r * POS + pos];
                const float tr = sl[r * POS + xp];
                v[r * 3 + 0] = (pos > 0) ? tl : 0.f;
                v[r * 3 + 1] = tc;
                v[r * 3 + 2] = (pos < POS - 1) ? tr : 0.f;
            }
            const float* wp = wt + (size_t)(cbs + c0 + cc) * 9;
#pragma unroll
            for (int o = 0; o < 27; ++o) {
                const float* w9 = wp + (size_t)o * CIN * 9;
#pragma unroll
                for (int k = 0; k < 9; ++k)
                    acc[o] = fmaf(w9[k], v[k], acc[o]);
            }
        }
        __syncthreads();
    }

#pragma unroll
    for (int o = 0; o < 27; ++o) red[(o * SPLIT + g) * POS + pos] = acc[o];
    __syncthreads();

    float* ob = om + (size_t)b * 27 * HH * WW + (size_t)row * WW;
    for (int i = tid; i < 27 * POS; i += NT) {
        const int o  = i / POS;
        const int px = i - o * POS;
        float s = bias[o];
#pragma unroll
        for (int gg = 0; gg < SPLIT; ++gg)
            s += red[(o * SPLIT + gg) * POS + px];
        ob[(size_t)o * HH * WW + px] = s;
    }
}

// ---------------- bilinear sampler: one KC=32 chunk into LDS (hi/lo bf16) ---
template <int CIN, int HH, int WW, int KS>
__device__ __forceinline__ void sample_chunk(
    const float* __restrict__ xb, const float* __restrict__ offy,
    const float* __restrict__ offx, const float* __restrict__ mskp,
    ushort* __restrict__ Shi, ushort* __restrict__ Slo,
    int tt, int p0, int kbase)
{
    const int pp = tt & 63;
    const int j0 = (tt >> 6) * 8;
    const int p  = p0 + pp;
    const int yy = p / WW;
    const int xx = p - yy * WW;
    uint hw[4] = {0, 0, 0, 0};
    uint lw[4] = {0, 0, 0, 0};
#pragma unroll
    for (int j = 0; j < 8; ++j) {
        const int kg = kbase + j0 + j;
        const int c  = (kg * 7282) >> 16;       // /9 (exact for kg<2304*)
        const int k9 = kg - c * 9;
        const int ky = (k9 * 11) >> 5;          // /3 for 0..8
        const int kx = k9 - ky * 3;
        const float py = (float)(yy + ky - 1) + offy[k9 * 64 + pp];
        const float px = (float)(xx + kx - 1) + offx[k9 * 64 + pp];
        const float y0f = floorf(py), x0f = floorf(px);
        const int   y0  = (int)y0f,  x0 = (int)x0f;
        const float wy1 = py - y0f, wy0 = 1.f - wy1;
        const float wx1 = px - x0f, wx0 = 1.f - wx1;
        const bool y0v = (y0 >= 0) && (y0 < HH);
        const bool y1v = (y0 + 1 >= 0) && (y0 + 1 < HH);
        const bool x0v = (x0 >= 0) && (x0 < WW);
        const bool x1v = (x0 + 1 >= 0) && (x0 + 1 < WW);
        const float* chp = xb + (size_t)c * (HH * WW);
        float s = 0.f;
        if (y0v && x0v) s += chp[y0 * WW + x0]           * (wy0 * wx0);
        if (y0v && x1v) s += chp[y0 * WW + x0 + 1]       * (wy0 * wx1);
        if (y1v && x0v) s += chp[(y0 + 1) * WW + x0]     * (wy1 * wx0);
        if (y1v && x1v) s += chp[(y0 + 1) * WW + x0 + 1] * (wy1 * wx1);
        s *= mskp[k9 * 64 + pp];
        const ushort h  = f2bf(s);
        const ushort l  = f2bf(s - bf2f(h));
        hw[j >> 1] |= ((uint)h) << ((j & 1) * 16);
        lw[j >> 1] |= ((uint)l) << ((j & 1) * 16);
    }
    uint4 hv; hv.x = hw[0]; hv.y = hw[1]; hv.z = hw[2]; hv.w = hw[3];
    uint4 lv; lv.x = lw[0]; lv.y = lw[1]; lv.z = lw[2]; lv.w = lw[3];
    *(uint4*)&Shi[pp * KS + j0] = hv;
    *(uint4*)&Slo[pp * KS + j0] = lv;
}

// ---------------- fused DCN on MFMA: sample + GEMM + bias + BN + ReLU -------
// Block tile: 64 positions x 128 co. 4 waves (KWAVES=1) each own 16 pos,
// all 8 co-mtiles. KWAVES=2: 8 waves, waves 4..7 take second K-half,
// LDS-reduced into waves 0..3 at the end. W frags load global->VGPR
// (per-lane 16B load IS the A fragment). S staged in LDS, double-buffered.
template <int CIN, int HH, int WW, int KWAVES>
__global__ __launch_bounds__(256 * KWAVES, 4 / KWAVES) void dcn_mfma_kernel(
    const float* __restrict__ xin,   // (B, CIN, HH, WW)
    const float* __restrict__ om,    // (B, 27, HH, WW)
    const ushort* __restrict__ whi,  // (128, CIN*9) bf16 hi
    const ushort* __restrict__ wlo,  // (128, CIN*9) bf16 lo
    const float* __restrict__ bias,
    const float* __restrict__ gam, const float* __restrict__ bet,
    const float* __restrict__ mu,  const float* __restrict__ var,
    float* __restrict__ out)         // (B, 128, HH*WW)
{
    constexpr int HW   = HH * WW;
    constexpr int K    = CIN * 9;
    constexpr int NT   = 256 * KWAVES;
    constexpr int KC   = 32;              // K per chunk (one MFMA K-step)
    constexpr int KS   = 40;              // S row stride (ushort), pad 8
    constexpr int KG   = K / KWAVES;      // K per wave-group
    constexpr int NCH  = KG / KC;         // 36 for both dcn1/dcn2
    constexpr int SBUF = 64 * KS;         // ushorts per (buf, hi|lo)

    extern __shared__ __align__(16) char smem[];
    float*  offy  = (float*)smem;             // 576
    float*  offx  = offy + 576;               // 576
    float*  mskp  = offx + 576;               // 576
    float*  invp  = mskp + 576;               // 128
    float*  shp   = invp + 128;               // 128
    ushort* Sbase = (ushort*)(shp + 128);     // KWAVES*4*SBUF ushorts
    float*  red   = (float*)Sbase;            // KWAVES=2 epilogue (aliases S)

    const int tid = threadIdx.x;
    const int nt  = HW / 64;
    const int b   = blockIdx.x / nt;
    const int p0  = (blockIdx.x - b * nt) * 64;

    const float* omb = om + (size_t)b * 27 * HW;
    for (int i = tid; i < 576; i += NT) {
        const int k = i >> 6, pp = i & 63;
        const int p = p0 + pp;
        offy[i] = omb[(size_t)k * HW + p];
        offx[i] = omb[(size_t)(9 + k) * HW + p];
        const float mv = omb[(size_t)(18 + k) * HW + p];
        mskp[i] = 1.0f / (1.0f + expf(-mv));
    }
    for (int i = tid; i < 128; i += NT) {
        const float iv = gam[i] * rsqrtf(var[i] + EPSV);
        invp[i] = iv;
        shp[i]  = bet[i] - mu[i] * iv + bias[i] * iv;
    }
    __syncthreads();

    const float* xb  = xin + (size_t)b * CIN * HW;
    const int lane = tid & 63;
    const int w    = tid >> 6;
    const int wq   = w & 3;                  // position quarter
    const int kgid = w >> 2;                 // K-group (0 or 1)
    const int tt   = tid & 255;              // index within K-group's 256 thr
    const int kbase_g = kgid * KG;

    ushort* S00 = Sbase + kgid * (4 * SBUF); // [buf][hi|lo] for this K-group

    f32x4 acc[8];
#pragma unroll
    for (int mt = 0; mt < 8; ++mt) acc[mt] = (f32x4){0.f, 0.f, 0.f, 0.f};

    const int mrow = lane & 15;
    const int kq   = lane >> 4;

    sample_chunk<CIN, HH, WW, KS>(xb, offy, offx, mskp,
                                  S00, S00 + SBUF, tt, p0, kbase_g);
    __syncthreads();

    for (int ch = 0; ch < NCH; ++ch) {
        const int cur = ch & 1;
        ushort* Sc = S00 + (cur * 2) * SBUF;
        if (ch + 1 < NCH) {
            ushort* Sn = S00 + ((cur ^ 1) * 2) * SBUF;
            sample_chunk<CIN, HH, WW, KS>(xb, offy, offx, mskp,
                                          Sn, Sn + SBUF, tt, p0,
                                          kbase_g + (ch + 1) * KC);
        }
        // B fragments from LDS: lane -> S[pos = wq*16+(l&15)][k0 = (l>>4)*8]
        const int boff = (wq * 16 + mrow) * KS + kq * 8;
        const short8 bh = *(const short8*)&Sc[boff];
        const short8 bl = *(const short8*)&Sc[SBUF + boff];
        // A fragments straight from global (L2-hot): W[co][k] row-major
        const size_t abase = (size_t)mrow * K + (size_t)(kbase_g + ch * KC)
                           + (size_t)(kq * 8);
#pragma unroll
        for (int mt = 0; mt < 8; ++mt) {
            const size_t ao = abase + (size_t)(mt * 16) * K;
            const short8 ah = *(const short8*)(whi + ao);
            const short8 al = *(const short8*)(wlo + ao);
            acc[mt] = __builtin_amdgcn_mfma_f32_16x16x32_bf16(al, bh, acc[mt], 0, 0, 0);
            acc[mt] = __builtin_amdgcn_mfma_f32_16x16x32_bf16(ah, bl, acc[mt], 0, 0, 0);
            acc[mt] = __builtin_amdgcn_mfma_f32_16x16x32_bf16(ah, bh, acc[mt], 0, 0, 0);
        }
        __syncthreads();
    }

    const int pcolb = wq * 16 + mrow;        // 0..63 within tile
    if constexpr (KWAVES == 2) {
        if (kgid == 1) {
#pragma unroll
            for (int mt = 0; mt < 8; ++mt)
#pragma unroll
                for (int r = 0; r < 4; ++r) {
                    const int co = mt * 16 + kq * 4 + r;
                    red[co * 68 + pcolb] = acc[mt][r];
                }
        }
        __syncthreads();
        if (kgid == 1) return;
#pragma unroll
        for (int mt = 0; mt < 8; ++mt)
#pragma unroll
            for (int r = 0; r < 4; ++r) {
                const int co = mt * 16 + kq * 4 + r;
                acc[mt][r] += red[co * 68 + pcolb];
            }
    }

    float* outb = out + (size_t)b * 128 * HW + p0 + pcolb;
#pragma unroll
    for (int mt = 0; mt < 8; ++mt)
#pragma unroll
        for (int r = 0; r < 4; ++r) {
            const int co = mt * 16 + kq * 4 + r;
            outb[(size_t)co * HW] = fmaxf(acc[mt][r] * invp[co] + shp[co], 0.f);
        }
}

// ---------------- depthwise transposed-conv upsample x2 (k=4, pad 2) --------
__global__ __launch_bounds__(256) void upsample_kernel(
    const float* __restrict__ y,    // (4,128,64,64)
    const float* __restrict__ wup,  // (128,1,4,4)
    float* __restrict__ out)        // (4,128,128,128)
{
    const int idx = blockIdx.x * 256 + threadIdx.x;
    const int ox = idx & 127;
    const int oy = (idx >> 7) & 127;
    const int c  = (idx >> 14) & 127;
    const int b  = idx >> 21;

    const float* yc = y + (size_t)(b * 128 + c) * 4096;
    const float* wc = wup + c * 16;

    float acc = 0.f;
#pragma unroll
    for (int ky = 0; ky < 4; ++ky) {
        const int qy = oy + ky - 2;
        if (qy & 1) continue;
        const int iy = qy >> 1;
        if (iy < 0 || iy >= 64) continue;
#pragma unroll
        for (int kx = 0; kx < 4; ++kx) {
            const int qx = ox + kx - 2;
            if (qx & 1) continue;
            const int ix = qx >> 1;
            if (ix < 0 || ix >= 64) continue;
            acc += yc[iy * 64 + ix] * wc[(3 - ky) * 4 + (3 - kx)];
        }
    }
    out[idx] = acc;
}

// ---------------------------------------------------------------------------
extern "C" void kernel_launch(void* const* d_in, const int* in_sizes, int n_in,
                              void* d_out, int out_size, void* d_ws, size_t ws_size,
                              hipStream_t stream) {
    const float* x      = (const float*)d_in[0];
    const float* w_off1 = (const float*)d_in[1];
    const float* b_off1 = (const float*)d_in[2];
    const float* w1     = (const float*)d_in[3];
    const float* b1     = (const float*)d_in[4];
    const float* g1v    = (const float*)d_in[5];
    const float* be1    = (const float*)d_in[6];
    const float* m1     = (const float*)d_in[7];
    const float* v1     = (const float*)d_in[8];
    const float* w_up   = (const float*)d_in[9];
    const float* w_off2 = (const float*)d_in[10];
    const float* b_off2 = (const float*)d_in[11];
    const float* w2     = (const float*)d_in[12];
    const float* b2     = (const float*)d_in[13];
    const float* g2v    = (const float*)d_in[14];
    const float* be2    = (const float*)d_in[15];
    const float* m2     = (const float*)d_in[16];
    const float* v2     = (const float*)d_in[17];

    float* ws  = (float*)d_ws;
    float* om1 = ws;                     // 4*27*4096   =   442368 f
    float* y1  = om1 + 442368;           // 4*128*4096  =  2097152 f
    float* up  = y1 + 2097152;           // 4*128*16384 =  8388608 f
    float* om2 = up + 8388608;           // 4*27*16384  =  1769472 f
    float* outf = (float*)d_out;

    // w1 split parked in `up` (dead until upsample overwrites it)
    ushort* w1hi = (ushort*)up;          // 294912 ushort
    ushort* w1lo = w1hi + 294912;
    // w2 split parked in `y1` (dead after upsample reads it)
    ushort* w2hi = (ushort*)y1;          // 147456 ushort
    ushort* w2lo = w2hi + 147456;

    // prep: split w1 -> bf16 hi/lo
    wsplit_kernel<<<(294912 + 255) / 256, 256, 0, stream>>>(w1, w1hi, w1lo, 294912);

    {   // om1 = conv3x3(x, w_off1) + b_off1
        dim3 grid(64, 4);
        conv_off_kernel<256, 64, 64, 8, 8><<<grid, 512, 0, stream>>>(
            x, w_off1, b_off1, om1);
    }
    // y1 = bn_relu(dcn1) — MFMA, 8 waves (2-way K-split), 256 blocks
    dcn_mfma_kernel<256, 64, 64, 2><<<4 * (4096 / 64), 512, 48896, stream>>>(
        x, om1, w1hi, w1lo, b1, g1v, be1, m1, v1, y1);
    // up = depthwise transposed upsample (clobbers w1 split — now dead)
    upsample_kernel<<<8388608 / 256, 256, 0, stream>>>(y1, w_up, up);
    // prep: split w2 -> bf16 hi/lo (y1 now dead)
    wsplit_kernel<<<(147456 + 255) / 256, 256, 0, stream>>>(w2, w2hi, w2lo, 147456);
    {   // om2 = conv3x3(up, w_off2) + b_off2
        dim3 grid(128, 4);
        conv_off_kernel<128, 128, 128, 2, 8><<<grid, 256, 0, stream>>>(
            up, w_off2, b_off2, om2);
    }
    // out = bn_relu(dcn2) — MFMA, 4 waves, 1024 blocks
    dcn_mfma_kernel<128, 128, 128, 1><<<4 * (16384 / 64), 256, 28416, stream>>>(
        up, om2, w2hi, w2lo, b2, g2v, be2, m2, v2, outf);
}